// Round 1
// baseline (667.335 us; speedup 1.0000x reference)
//
#include <hip/hip_runtime.h>

#define N_NODES 50000
#define N_EDGES 800000

// Broadcast lane k's value to all lanes (uniform k) via v_readlane.
__device__ __forceinline__ float bcastf(float x, int k) {
  return __uint_as_float(__builtin_amdgcn_readlane(__float_as_uint(x), (unsigned)k));
}

// Kernel A: per-node projections.
// NP[n][0:64]   = n_feat[n] @ W_a[0:128]     (P_ad)
// NP[n][64:128] = n_feat[n] @ W_a[192:320]   (P_as)
// NP[n][128:192]= n_feat[n] @ W_T[0:128]     (P_td)
// NP[n][192:256]= n_feat[n] @ W_T[192:320]   (P_ts)
// NP[n][256:320]= n_feat[n] @ W_e            (P_e)
__global__ __launch_bounds__(64) void node_proj(
    const float* __restrict__ n_feat, const float* __restrict__ W_a,
    const float* __restrict__ W_T, const float* __restrict__ W_e,
    float* __restrict__ NP) {
  __shared__ float sN[16 * 128];
  const int lane = threadIdx.x;
  const int n0 = blockIdx.x * 16;

  // Stage 16 node rows (8 KB) coalesced as float4.
  float4* sN4 = (float4*)sN;
  const float4* nf4 = (const float4*)(n_feat + (size_t)n0 * 128);
  #pragma unroll
  for (int t = 0; t < 8; ++t) sN4[t * 64 + lane] = nf4[t * 64 + lane];
  __syncthreads();

  float acc[5][16];
  #pragma unroll
  for (int q = 0; q < 5; ++q)
    #pragma unroll
    for (int i = 0; i < 16; ++i) acc[q][i] = 0.f;

  // lane owns column `lane` of all 5 projections; 16 nodes register-blocked.
  for (int k = 0; k < 128; ++k) {
    float w0 = W_a[k * 64 + lane];          // Wa_d col
    float w1 = W_a[(192 + k) * 64 + lane];  // Wa_s col
    float w2 = W_T[k * 64 + lane];          // Wt_d col
    float w3 = W_T[(192 + k) * 64 + lane];  // Wt_s col
    float w4 = W_e[k * 64 + lane];          // W_e col
    #pragma unroll
    for (int i = 0; i < 16; ++i) {
      float nv = sN[i * 128 + k];  // uniform address -> LDS broadcast
      acc[0][i] = __builtin_fmaf(nv, w0, acc[0][i]);
      acc[1][i] = __builtin_fmaf(nv, w1, acc[1][i]);
      acc[2][i] = __builtin_fmaf(nv, w2, acc[2][i]);
      acc[3][i] = __builtin_fmaf(nv, w3, acc[3][i]);
      acc[4][i] = __builtin_fmaf(nv, w4, acc[4][i]);
    }
  }
  #pragma unroll
  for (int i = 0; i < 16; ++i)
    #pragma unroll
    for (int q = 0; q < 5; ++q)
      NP[(size_t)(n0 + i) * 320 + q * 64 + lane] = acc[q][i];
}

// Kernel B: edge GEMM (e_feat @ [Wa_e|Wt_e|W_ee]) + fused softmax-numerator
// scatter + new_e_feat write. No max-subtraction (shift-invariant, logits
// bounded ~|10| so exp() is safe in fp32).
__global__ __launch_bounds__(256) void edge_pass(
    const float* __restrict__ e_feat, const int* __restrict__ src,
    const int* __restrict__ dst, const float* __restrict__ W_a,
    const float* __restrict__ W_T, const float* __restrict__ W_ee,
    const float* __restrict__ prelu_a, const float* __restrict__ NP,
    float* __restrict__ denom, float* __restrict__ numer,
    float* __restrict__ out_e) {
  // sW[k][0:64]=Wa_e row k, [64:128]=Wt_e row k, [128:192]=W_ee row k
  __shared__ float sW[64 * 192];
  const int tid = threadIdx.x;
  const int lane = tid & 63;
  const int wid = tid >> 6;

  for (int t = tid; t < 64 * 192; t += 256) {
    int k = t / 192, c = t % 192;
    float v;
    if (c < 64)        v = W_a[(128 + k) * 64 + c];         // Wa_e = W_a rows 128..191
    else if (c < 128)  v = W_T[(128 + k) * 64 + (c - 64)];  // Wt_e
    else               v = W_ee[k * 64 + (c - 128)];
    sW[t] = v;
  }
  __syncthreads();
  const float pa = prelu_a[0];

  for (int g = 0; g < 8; ++g) {
    const int e0 = blockIdx.x * 256 + g * 32 + wid * 8;
    float ef[8], aa[8], at[8], ae[8];
    #pragma unroll
    for (int i = 0; i < 8; ++i) {
      ef[i] = e_feat[(size_t)(e0 + i) * 64 + lane];  // coalesced
      aa[i] = 0.f; at[i] = 0.f; ae[i] = 0.f;
    }
    // 64x(8 edges)x(192 cols) GEMM: lane = output col, readlane-broadcast A.
    #pragma unroll 4
    for (int k = 0; k < 64; ++k) {
      float wa = sW[k * 192 + lane];
      float wt = sW[k * 192 + 64 + lane];
      float we = sW[k * 192 + 128 + lane];
      #pragma unroll
      for (int i = 0; i < 8; ++i) {
        float b = bcastf(ef[i], k);  // e_feat[e_i][k]
        aa[i] = __builtin_fmaf(b, wa, aa[i]);
        at[i] = __builtin_fmaf(b, wt, at[i]);
        ae[i] = __builtin_fmaf(b, we, ae[i]);
      }
    }
    #pragma unroll
    for (int i = 0; i < 8; ++i) {
      int e = e0 + i;
      int s = src[e], d = dst[e];  // uniform -> scalar loads
      const float* NPs = NP + (size_t)s * 320;
      const float* NPd = NP + (size_t)d * 320;
      float la = NPd[lane] + aa[i] + NPs[64 + lane];
      float lg = la >= 0.f ? la : pa * la;
      float ex = __expf(lg);
      float un = NPd[128 + lane] + at[i] + NPs[192 + lane];
      atomicAdd(denom + (size_t)d * 64 + lane, ex);
      atomicAdd(numer + (size_t)d * 64 + lane, ex * un);
      out_e[(size_t)e * 64 + lane] = NPs[256 + lane] + NPd[256 + lane] + ae[i];
    }
  }
}

// Kernel C: new_n_feat = has_msg ? num/denom + b_T : 0. denom>0 <=> deg>0.
__global__ __launch_bounds__(256) void node_final(
    const float* __restrict__ denom, const float* __restrict__ numer,
    const float* __restrict__ b_T, float* __restrict__ out_n) {
  int t = blockIdx.x * 256 + threadIdx.x;
  if (t >= N_NODES * 64) return;
  float dn = denom[t];
  out_n[t] = dn > 0.f ? numer[t] / dn + b_T[t & 63] : 0.f;
}

extern "C" void kernel_launch(void* const* d_in, const int* in_sizes, int n_in,
                              void* d_out, int out_size, void* d_ws, size_t ws_size,
                              hipStream_t stream) {
  const float* n_feat  = (const float*)d_in[0];
  const float* e_feat  = (const float*)d_in[1];
  const int*   src     = (const int*)d_in[2];
  const int*   dst     = (const int*)d_in[3];
  const float* W_a     = (const float*)d_in[4];
  const float* W_T     = (const float*)d_in[5];
  const float* b_T     = (const float*)d_in[6];
  const float* W_e     = (const float*)d_in[7];
  const float* W_ee    = (const float*)d_in[8];
  const float* prelu_a = (const float*)d_in[9];

  float* out_n = (float*)d_out;
  float* out_e = out_n + (size_t)N_NODES * 64;

  // Workspace layout: NP (50000*320 f32 = 64 MB) | denom (12.8 MB) | num (12.8 MB)
  float* NP    = (float*)d_ws;
  float* denom = NP + (size_t)N_NODES * 320;
  float* numer = denom + (size_t)N_NODES * 64;

  hipMemsetAsync(denom, 0, (size_t)N_NODES * 64 * 2 * sizeof(float), stream);
  node_proj<<<N_NODES / 16, 64, 0, stream>>>(n_feat, W_a, W_T, W_e, NP);
  edge_pass<<<N_EDGES / 256, 256, 0, stream>>>(e_feat, src, dst, W_a, W_T, W_ee,
                                               prelu_a, NP, denom, numer, out_e);
  node_final<<<(N_NODES * 64 + 255) / 256, 256, 0, stream>>>(denom, numer, b_T, out_n);
}